// Round 22
// baseline (59.438 us; speedup 1.0000x reference)
//
#include <hip/hip_runtime.h>
#include <cstddef>

#define SB 2
#define SS 4096
#define SH 8
#define SD 64
#define SP 64          // half-window
#define SNO 129        // W+1 offsets
#define TQ 16          // query tokens per attn block
#define WN 144         // TQ + 2*SP key window
#define NT16 (SS/TQ)   // 256 tiles per batch
#define SSTR 168       // Ss row stride (f16); cols [WN,160) zero-padded for PV

typedef _Float16 f16;
typedef __attribute__((ext_vector_type(8))) _Float16 f16x8;
typedef __attribute__((ext_vector_type(4))) float floatx4;

union f16frag { f16 h[8]; ushort4 u4[2]; f16x8 v; };

__device__ __forceinline__ float fast_tanh(float x) {
  // 1 - 2/(e^{2x}+1): valid for ALL x (x->+inf: rcp(inf)=0 -> 1; x->-inf: rcp(1)=1 -> -1)
  float e = __expf(2.0f * x);
  return 1.0f - 2.0f * __builtin_amdgcn_rcpf(e + 1.0f);
}

__device__ __forceinline__ void cvt16(const float* __restrict__ src, f16* __restrict__ dst) {
  float4 x0 = *(const float4*)(src);
  float4 x1 = *(const float4*)(src + 4);
  float4 x2 = *(const float4*)(src + 8);
  float4 x3 = *(const float4*)(src + 12);
  f16frag a, c;
  a.h[0]=(f16)x0.x; a.h[1]=(f16)x0.y; a.h[2]=(f16)x0.z; a.h[3]=(f16)x0.w;
  a.h[4]=(f16)x1.x; a.h[5]=(f16)x1.y; a.h[6]=(f16)x1.z; a.h[7]=(f16)x1.w;
  c.h[0]=(f16)x2.x; c.h[1]=(f16)x2.y; c.h[2]=(f16)x2.z; c.h[3]=(f16)x2.w;
  c.h[4]=(f16)x3.x; c.h[5]=(f16)x3.y; c.h[6]=(f16)x3.z; c.h[7]=(f16)x3.w;
  *(ushort4*)(dst)      = a.u4[0];
  *(ushort4*)(dst + 4)  = a.u4[1];
  *(ushort4*)(dst + 8)  = c.u4[0];
  *(ushort4*)(dst + 12) = c.u4[1];
}

// ---------------- prep: project Q,K + convert/transpose V + zero out ----------------
__global__ __launch_bounds__(256) void prep_kernel(
    const float* __restrict__ q, const float* __restrict__ k, const float* __restrict__ v,
    const float* __restrict__ Wq, const float* __restrict__ bq,
    const float* __restrict__ Wk, const float* __restrict__ bk,
    f16* __restrict__ Qf, f16* __restrict__ Kf, f16* __restrict__ Vt,
    float* __restrict__ outp)
{
  __shared__ f16 sWq[64*72], sWk[64*72], sQr[64*72], sKr[64*72], sVr[64*72];
  __shared__ float sbq[64], sbk[64];

  int t = threadIdx.x;
  int blk = blockIdx.x;
  int x = blk & 7, j = blk >> 3;
  int c = x*8 + (j & 7);
  int h = (j >> 3) & 7;
  int b = j >> 6;
  int s0 = c * 64;

  // zero the out accumulator: 1024 blocks x 512 floats (float2/thread)
  *(float2*)(outp + (size_t)blk * 512 + t * 2) = make_float2(0.f, 0.f);

  int dr = t >> 2, e0 = (t & 3) * 16;
  cvt16(Wq + dr*64 + e0, &sWq[dr*72 + e0]);
  cvt16(Wk + dr*64 + e0, &sWk[dr*72 + e0]);
  {
    size_t rbase = ((size_t)(b*SS + s0 + dr)) * (SH*SD) + h*SD + e0;
    cvt16(q + rbase, &sQr[dr*72 + e0]);
    cvt16(k + rbase, &sKr[dr*72 + e0]);
    cvt16(v + rbase, &sVr[dr*72 + e0]);
  }
  if (t < 64) { sbq[t] = bq[t]; sbk[t] = bk[t]; }
  __syncthreads();

  int lane = t & 63, wave = t >> 6;
  int r16 = lane & 15, g = lane >> 4;
  size_t hsbase = (size_t)(b*SH + h) * SS;

  #pragma unroll
  for (int jj = 0; jj < 4; ++jj) {
    int tt = wave + 4*jj;
    int si = tt >> 2, dj = tt & 3;
    floatx4 accq = {0.f,0.f,0.f,0.f}, acck = {0.f,0.f,0.f,0.f};
    #pragma unroll
    for (int e = 0; e < 64; e += 32) {
      f16x8 aq = *(const f16x8*)&sQr[(si*16 + r16)*72 + e + g*8];
      f16x8 ak = *(const f16x8*)&sKr[(si*16 + r16)*72 + e + g*8];
      f16x8 wq8 = *(const f16x8*)&sWq[(dj*16 + r16)*72 + e + g*8];
      f16x8 wk8 = *(const f16x8*)&sWk[(dj*16 + r16)*72 + e + g*8];
      accq = __builtin_amdgcn_mfma_f32_16x16x32_f16(aq, wq8, accq, 0, 0, 0);
      acck = __builtin_amdgcn_mfma_f32_16x16x32_f16(ak, wk8, acck, 0, 0, 0);
    }
    float biasq = sbq[dj*16 + r16];
    float biask = sbk[dj*16 + r16];
    #pragma unroll
    for (int rr = 0; rr < 4; ++rr) {
      int srow = s0 + si*16 + g*4 + rr;
      Qf[(hsbase + srow)*64 + dj*16 + r16] = (f16)(accq[rr] + biasq);
      Kf[(hsbase + srow)*64 + dj*16 + r16] = (f16)(acck[rr] + biask);
    }
  }
  {
    int d = t >> 2, p4 = t & 3, sc0 = p4 * 16;
    f16frag a, c2;
    #pragma unroll
    for (int j2 = 0; j2 < 8; ++j2) a.h[j2] = sVr[(sc0 + j2)*72 + d];
    #pragma unroll
    for (int j2 = 0; j2 < 8; ++j2) c2.h[j2] = sVr[(sc0 + 8 + j2)*72 + d];
    f16* dst = Vt + ((size_t)(b*SH + h)*64 + d)*SS + s0 + sc0;
    *(ushort4*)dst       = a.u4[0];
    *(ushort4*)(dst + 4) = a.u4[1];
    *(ushort4*)(dst + 8) = c2.u4[0];
    *(ushort4*)(dst + 12)= c2.u4[1];
  }
}

// ---------------- fused attention: wave = head; ONE barrier, no cross-wave deps ---
// 512 blocks x 512 threads; LDS 47.1KB -> 2 blocks/CU, 16 waves/CU, all resident.
// af written DIRECTLY during scores (4B stores; the 8 h-siblings are waves of the
// SAME block -> same L2, same time window -> lines merge). out via atomicAdd
// (zeroed by prep). No sAF, no reduce, no epilogue barriers.
__global__ __launch_bounds__(512, 4) void attn_fused(
    const f16* __restrict__ Qf, const f16* __restrict__ Kf, const f16* __restrict__ Vt,
    const float* __restrict__ ocpe, float* __restrict__ af, float* __restrict__ outp)
{
  __shared__ f16 sPriv[SH][TQ*SSTR];    // 43,008 B per-head S[i][y] (wave-private)
  __shared__ float sObT[SH*SNO];        // 4,128 B  [h][o]

  int t = threadIdx.x;
  int lane = t & 63, wave = t >> 6;
  int r16 = lane & 15, g = lane >> 4;

  // XCD-span mapping (matches prep)
  int blk = blockIdx.x;
  int x = blk & 7, j = blk >> 3;
  int t16 = x*32 + (j & 31);
  int b = j >> 5;
  int t0 = t16 * TQ, yg0 = t0 - SP;

  int h = wave;
  const f16* qb = Qf + ((size_t)(b*SH + h)*SS + t0 + r16)*64;
  f16x8 qa0 = *(const f16x8*)(qb + g*8);
  f16x8 qa1 = *(const f16x8*)(qb + 32 + g*8);

  for (int idx = t; idx < SNO*SH; idx += 512) {
    int o = idx >> 3, h2 = idx & 7;
    sObT[h2*SNO + o] = ocpe[idx];
  }
  f16* priv = &sPriv[wave][0];
  #pragma unroll
  for (int jj = 0; jj < 4; ++jj)
    priv[r16*SSTR + WN + g*4 + jj] = (f16)0.f;

  __syncthreads();   // the ONLY barrier: sObT visible

  const float* ob = &sObT[h*SNO];
  const f16* kbase = Kf + ((size_t)(b*SH + h)*SS)*64;
  float* afh = af + ((size_t)(b*SS + t0) * SNO) * SH + h;
  floatx4 acc2[4] = {{0.f,0.f,0.f,0.f},{0.f,0.f,0.f,0.f},{0.f,0.f,0.f,0.f},{0.f,0.f,0.f,0.f}};

  bool interior = (t16 >= 4) & (t16 <= 250);   // block-uniform

  if (interior) {
    const f16* krow = kbase + (size_t)(yg0 + r16) * 64 + g*8;
    #pragma unroll
    for (int yy = 0; yy < 9; ++yy) {
      f16x8 kb0 = *(const f16x8*)(krow + yy*1024);
      f16x8 kb1 = *(const f16x8*)(krow + yy*1024 + 32);
      floatx4 acc = {0.f,0.f,0.f,0.f};
      acc = __builtin_amdgcn_mfma_f32_16x16x32_f16(qa0, kb0, acc, 0, 0, 0);
      acc = __builtin_amdgcn_mfma_f32_16x16x32_f16(qa1, kb1, acc, 0, 0, 0);
      int y = yy*16 + r16;
      #pragma unroll
      for (int rr = 0; rr < 4; ++rr) {
        int i = g*4 + rr;
        int o = y - i;
        bool ook = (o >= 0) & (o <= 2*SP);
        f16 ah = (f16)0.f;
        if (ook) ah = (f16)fast_tanh(acc[rr] + ob[o]);
        priv[i*SSTR + y] = ah;
        if (ook) afh[(i*SNO + o) * SH] = (float)ah;   // direct af store
      }
    }
    const f16* vrow = Vt + ((size_t)(b*SH + h)*64 + r16)*SS + yg0 + g*8;
    #pragma unroll
    for (int ks = 0; ks < 5; ++ks) {
      int yb = ks*32 + g*8;
      f16x8 a0 = *(const f16x8*)&priv[r16*SSTR + yb];
      #pragma unroll
      for (int dq = 0; dq < 4; ++dq) {
        f16x8 bv = *(const f16x8*)(vrow + (size_t)(dq*16)*SS + ks*32);
        acc2[dq] = __builtin_amdgcn_mfma_f32_16x16x32_f16(a0, bv, acc2[dq], 0, 0, 0);
      }
    }
  } else {
    #pragma unroll
    for (int yy = 0; yy < 9; ++yy) {
      int y = yy*16 + r16;
      int ygr = yg0 + y;
      int ygc = min(max(ygr, 0), SS-1);
      bool yok = (ygr >= 0) & (ygr < SS);
      const f16* kr = kbase + (size_t)ygc * 64;
      f16x8 kb0 = *(const f16x8*)(kr + g*8);
      f16x8 kb1 = *(const f16x8*)(kr + 32 + g*8);
      floatx4 acc = {0.f,0.f,0.f,0.f};
      acc = __builtin_amdgcn_mfma_f32_16x16x32_f16(qa0, kb0, acc, 0, 0, 0);
      acc = __builtin_amdgcn_mfma_f32_16x16x32_f16(qa1, kb1, acc, 0, 0, 0);
      #pragma unroll
      for (int rr = 0; rr < 4; ++rr) {
        int i = g*4 + rr;
        int o = y - i;
        bool ook = (o >= 0) & (o <= 2*SP);
        f16 ah = (f16)0.f;
        if (yok & ook) ah = (f16)fast_tanh(acc[rr] + ob[o]);
        priv[i*SSTR + y] = ah;
        if (ook) afh[(i*SNO + o) * SH] = (float)ah;   // masked entries store 0
      }
    }
    const f16* vb0 = Vt + ((size_t)(b*SH + h)*64 + r16)*SS;
    #pragma unroll
    for (int ks = 0; ks < 5; ++ks) {
      int yb = ks*32 + g*8;
      int ygr = yg0 + yb;
      int ygc = min(max(ygr, 0), SS-8);
      f16x8 a0 = *(const f16x8*)&priv[r16*SSTR + yb];
      #pragma unroll
      for (int dq = 0; dq < 4; ++dq) {
        f16x8 bv = *(const f16x8*)(vb0 + (size_t)(dq*16)*SS + ygc);
        acc2[dq] = __builtin_amdgcn_mfma_f32_16x16x32_f16(a0, bv, acc2[dq], 0, 0, 0);
      }
    }
  }

  // out: per-wave atomic accumulation (outp zeroed by prep; 8 adds/address)
  #pragma unroll
  for (int dq = 0; dq < 4; ++dq)
    #pragma unroll
    for (int rr = 0; rr < 4; ++rr)
      atomicAdd(outp + ((size_t)b*SS + t0 + g*4 + rr)*64 + dq*16 + r16, acc2[dq][rr]);
}

extern "C" void kernel_launch(void* const* d_in, const int* in_sizes, int n_in,
                              void* d_out, int out_size, void* d_ws, size_t ws_size,
                              hipStream_t stream) {
  const float* q    = (const float*)d_in[0];
  const float* k    = (const float*)d_in[1];
  const float* v    = (const float*)d_in[2];
  const float* Wq   = (const float*)d_in[3];
  const float* bq   = (const float*)d_in[4];
  const float* Wk   = (const float*)d_in[5];
  const float* bk   = (const float*)d_in[6];
  const float* ocpe = (const float*)d_in[7];

  // ws: Kf (8.39MB) + Vt (8.39MB) + Qf (8.39MB) = 25.2MB (fits proven 33.7MB)
  f16* Kf = (f16*)d_ws;
  f16* Vt = Kf + (size_t)SB*SH*SS*SD;
  f16* Qf = Vt + (size_t)SB*SH*SS*SD;

  float* af = (float*)d_out;
  float* op = af + (size_t)SB*SS*SNO*SH;

  prep_kernel<<<SB*SH*64, 256, 0, stream>>>(q, k, v, Wq, bq, Wk, bk, Qf, Kf, Vt, op);
  attn_fused<<<SB*NT16, 512, 0, stream>>>(Qf, Kf, Vt, ocpe, af, op);
}

// Round 23
// 44.415 us; speedup vs baseline: 1.3382x; 1.3382x over previous
//
#include <hip/hip_runtime.h>
#include <cstddef>

#define SB 2
#define SS 4096
#define SH 8
#define SD 64
#define SP 64          // half-window
#define SNO 129        // W+1 offsets
#define TQ 16          // query tokens per attn block
#define WN 144         // TQ + 2*SP key window
#define NT16 (SS/TQ)   // 256 tiles per batch
#define SSTR 168       // Ss row stride (f16); cols [WN,160) zero-padded for PV

typedef _Float16 f16;
typedef __attribute__((ext_vector_type(8))) _Float16 f16x8;
typedef __attribute__((ext_vector_type(4))) float floatx4;

union f16frag { f16 h[8]; ushort4 u4[2]; f16x8 v; };
union pack4 { f16 h[4]; ushort4 u; };

__device__ __forceinline__ float fast_tanh(float x) {
  // 1 - 2/(e^{2x}+1): exact for all x (x->+inf -> 1, x->-inf -> -1); no branches
  float e = __expf(2.0f * x);
  return 1.0f - 2.0f * __builtin_amdgcn_rcpf(e + 1.0f);
}

__device__ __forceinline__ void cvt16(const float* __restrict__ src, f16* __restrict__ dst) {
  float4 x0 = *(const float4*)(src);
  float4 x1 = *(const float4*)(src + 4);
  float4 x2 = *(const float4*)(src + 8);
  float4 x3 = *(const float4*)(src + 12);
  f16frag a, c;
  a.h[0]=(f16)x0.x; a.h[1]=(f16)x0.y; a.h[2]=(f16)x0.z; a.h[3]=(f16)x0.w;
  a.h[4]=(f16)x1.x; a.h[5]=(f16)x1.y; a.h[6]=(f16)x1.z; a.h[7]=(f16)x1.w;
  c.h[0]=(f16)x2.x; c.h[1]=(f16)x2.y; c.h[2]=(f16)x2.z; c.h[3]=(f16)x2.w;
  c.h[4]=(f16)x3.x; c.h[5]=(f16)x3.y; c.h[6]=(f16)x3.z; c.h[7]=(f16)x3.w;
  *(ushort4*)(dst)      = a.u4[0];
  *(ushort4*)(dst + 4)  = a.u4[1];
  *(ushort4*)(dst + 8)  = c.u4[0];
  *(ushort4*)(dst + 12) = c.u4[1];
}

// ---------------- prep (unchanged R18: XCD-span mapping) ----------------
__global__ __launch_bounds__(256) void prep_kernel(
    const float* __restrict__ q, const float* __restrict__ k, const float* __restrict__ v,
    const float* __restrict__ Wq, const float* __restrict__ bq,
    const float* __restrict__ Wk, const float* __restrict__ bk,
    f16* __restrict__ Qf, f16* __restrict__ Kf, f16* __restrict__ Vt)
{
  __shared__ f16 sWq[64*72], sWk[64*72], sQr[64*72], sKr[64*72], sVr[64*72];
  __shared__ float sbq[64], sbk[64];

  int t = threadIdx.x;
  int blk = blockIdx.x;
  int x = blk & 7, j = blk >> 3;
  int c = x*8 + (j & 7);
  int h = (j >> 3) & 7;
  int b = j >> 6;
  int s0 = c * 64;

  int dr = t >> 2, e0 = (t & 3) * 16;
  cvt16(Wq + dr*64 + e0, &sWq[dr*72 + e0]);
  cvt16(Wk + dr*64 + e0, &sWk[dr*72 + e0]);
  {
    size_t rbase = ((size_t)(b*SS + s0 + dr)) * (SH*SD) + h*SD + e0;
    cvt16(q + rbase, &sQr[dr*72 + e0]);
    cvt16(k + rbase, &sKr[dr*72 + e0]);
    cvt16(v + rbase, &sVr[dr*72 + e0]);
  }
  if (t < 64) { sbq[t] = bq[t]; sbk[t] = bk[t]; }
  __syncthreads();

  int lane = t & 63, wave = t >> 6;
  int r16 = lane & 15, g = lane >> 4;
  size_t hsbase = (size_t)(b*SH + h) * SS;

  #pragma unroll
  for (int jj = 0; jj < 4; ++jj) {
    int tt = wave + 4*jj;
    int si = tt >> 2, dj = tt & 3;
    floatx4 accq = {0.f,0.f,0.f,0.f}, acck = {0.f,0.f,0.f,0.f};
    #pragma unroll
    for (int e = 0; e < 64; e += 32) {
      f16x8 aq = *(const f16x8*)&sQr[(si*16 + r16)*72 + e + g*8];
      f16x8 ak = *(const f16x8*)&sKr[(si*16 + r16)*72 + e + g*8];
      f16x8 wq8 = *(const f16x8*)&sWq[(dj*16 + r16)*72 + e + g*8];
      f16x8 wk8 = *(const f16x8*)&sWk[(dj*16 + r16)*72 + e + g*8];
      accq = __builtin_amdgcn_mfma_f32_16x16x32_f16(aq, wq8, accq, 0, 0, 0);
      acck = __builtin_amdgcn_mfma_f32_16x16x32_f16(ak, wk8, acck, 0, 0, 0);
    }
    float biasq = sbq[dj*16 + r16];
    float biask = sbk[dj*16 + r16];
    #pragma unroll
    for (int rr = 0; rr < 4; ++rr) {
      int srow = s0 + si*16 + g*4 + rr;
      Qf[(hsbase + srow)*64 + dj*16 + r16] = (f16)(accq[rr] + biasq);
      Kf[(hsbase + srow)*64 + dj*16 + r16] = (f16)(acck[rr] + biask);
    }
  }
  {
    int d = t >> 2, p4 = t & 3, sc0 = p4 * 16;
    f16frag a, c2;
    #pragma unroll
    for (int j2 = 0; j2 < 8; ++j2) a.h[j2] = sVr[(sc0 + j2)*72 + d];
    #pragma unroll
    for (int j2 = 0; j2 < 8; ++j2) c2.h[j2] = sVr[(sc0 + 8 + j2)*72 + d];
    f16* dst = Vt + ((size_t)(b*SH + h)*64 + d)*SS + s0 + sc0;
    *(ushort4*)dst       = a.u4[0];
    *(ushort4*)(dst + 4) = a.u4[1];
    *(ushort4*)(dst + 8) = c2.u4[0];
    *(ushort4*)(dst + 12)= c2.u4[1];
  }
}

// ---------------- fused attention (R18 structure + swapped scores + rcp-tanh) ----
// Scores: mfma(K,Q) -> lane holds fixed i=r16 and 4 consecutive y -> ONE b64 priv
// store per y-tile (was 4 scalar); sAF scatter unchanged (2-way aliasing, free).
// Epilogue: R18's proven sAF linear copy + priv f32 dump + cross-head reduce.
__global__ __launch_bounds__(512, 4) void attn_fused(
    const f16* __restrict__ Qf, const f16* __restrict__ Kf, const f16* __restrict__ Vt,
    const float* __restrict__ ocpe, float* __restrict__ af, float* __restrict__ outp)
{
  __shared__ f16 sPriv[SH][TQ*SSTR];    // 43,008 B (per-wave S[i][y]; later f32 partials)
  __shared__ f16 sAF[TQ*SNO*SH];        // 33,024 B  [i][o][h]
  __shared__ float sObT[SH*SNO];        // 4,128 B   [h][o]

  int t = threadIdx.x;
  int lane = t & 63, wave = t >> 6;
  int r16 = lane & 15, g = lane >> 4;

  // XCD-span mapping (matches prep)
  int blk = blockIdx.x;
  int x = blk & 7, j = blk >> 3;
  int t16 = x*32 + (j & 31);
  int b = j >> 5;
  int t0 = t16 * TQ, yg0 = t0 - SP;

  int h = wave;
  const f16* qb = Qf + ((size_t)(b*SH + h)*SS + t0 + r16)*64;
  f16x8 qa0 = *(const f16x8*)(qb + g*8);
  f16x8 qa1 = *(const f16x8*)(qb + 32 + g*8);

  for (int idx = t; idx < SNO*SH; idx += 512) {
    int o = idx >> 3, h2 = idx & 7;
    sObT[h2*SNO + o] = ocpe[idx];
  }
  f16* priv = &sPriv[wave][0];
  #pragma unroll
  for (int jj = 0; jj < 4; ++jj)
    priv[r16*SSTR + WN + g*4 + jj] = (f16)0.f;

  __syncthreads();   // sObT visible

  const float* ob = &sObT[h*SNO];
  const f16* kbase = Kf + ((size_t)(b*SH + h)*SS)*64;
  floatx4 acc2[4] = {{0.f,0.f,0.f,0.f},{0.f,0.f,0.f,0.f},{0.f,0.f,0.f,0.f},{0.f,0.f,0.f,0.f}};

  bool interior = (t16 >= 4) & (t16 <= 250);   // block-uniform

  if (interior) {
    const f16* krow = kbase + (size_t)(yg0 + r16) * 64 + g*8;
    #pragma unroll
    for (int yy = 0; yy < 9; ++yy) {
      f16x8 kb0 = *(const f16x8*)(krow + yy*1024);
      f16x8 kb1 = *(const f16x8*)(krow + yy*1024 + 32);
      floatx4 acc = {0.f,0.f,0.f,0.f};
      acc = __builtin_amdgcn_mfma_f32_16x16x32_f16(kb0, qa0, acc, 0, 0, 0);
      acc = __builtin_amdgcn_mfma_f32_16x16x32_f16(kb1, qa1, acc, 0, 0, 0);
      int y0 = yy*16 + g*4;
      int i = r16;
      pack4 pk;
      #pragma unroll
      for (int rr = 0; rr < 4; ++rr) {
        int o = y0 + rr - i;            // o = y - i
        bool ook = (o >= 0) & (o <= 2*SP);
        f16 ah = (f16)0.f;
        if (ook) {
          ah = (f16)fast_tanh(acc[rr] + ob[o]);
          sAF[((size_t)i*SNO + o)*SH + h] = ah;
        }
        pk.h[rr] = ah;
      }
      *(ushort4*)&priv[i*SSTR + y0] = pk.u;
    }
    const f16* vrow = Vt + ((size_t)(b*SH + h)*64 + r16)*SS + yg0 + g*8;
    #pragma unroll
    for (int ks = 0; ks < 5; ++ks) {
      int yb = ks*32 + g*8;
      f16x8 a0 = *(const f16x8*)&priv[r16*SSTR + yb];
      #pragma unroll
      for (int dq = 0; dq < 4; ++dq) {
        f16x8 bv = *(const f16x8*)(vrow + (size_t)(dq*16)*SS + ks*32);
        acc2[dq] = __builtin_amdgcn_mfma_f32_16x16x32_f16(a0, bv, acc2[dq], 0, 0, 0);
      }
    }
  } else {
    #pragma unroll
    for (int yy = 0; yy < 9; ++yy) {
      int ldr = yg0 + yy*16 + r16;
      int ldc = min(max(ldr, 0), SS-1);
      const f16* kr = kbase + (size_t)ldc * 64;
      f16x8 kb0 = *(const f16x8*)(kr + g*8);
      f16x8 kb1 = *(const f16x8*)(kr + 32 + g*8);
      floatx4 acc = {0.f,0.f,0.f,0.f};
      acc = __builtin_amdgcn_mfma_f32_16x16x32_f16(kb0, qa0, acc, 0, 0, 0);
      acc = __builtin_amdgcn_mfma_f32_16x16x32_f16(kb1, qa1, acc, 0, 0, 0);
      int y0 = yy*16 + g*4;
      int i = r16;
      pack4 pk;
      #pragma unroll
      for (int rr = 0; rr < 4; ++rr) {
        int y = y0 + rr;
        int ygr = yg0 + y;
        int o = y - i;
        bool ok = (ygr >= 0) & (ygr < SS) & (o >= 0) & (o <= 2*SP);
        f16 ah = (f16)0.f;
        if (ok) ah = (f16)fast_tanh(acc[rr] + ob[o]);
        if ((o >= 0) & (o <= 2*SP)) sAF[((size_t)i*SNO + o)*SH + h] = ah;
        pk.h[rr] = ah;
      }
      *(ushort4*)&priv[i*SSTR + y0] = pk.u;
    }
    const f16* vb0 = Vt + ((size_t)(b*SH + h)*64 + r16)*SS;
    #pragma unroll
    for (int ks = 0; ks < 5; ++ks) {
      int yb = ks*32 + g*8;
      int ygr = yg0 + yb;
      int ygc = min(max(ygr, 0), SS-8);
      f16x8 a0 = *(const f16x8*)&priv[r16*SSTR + yb];
      #pragma unroll
      for (int dq = 0; dq < 4; ++dq) {
        f16x8 bv = *(const f16x8*)(vb0 + (size_t)(dq*16)*SS + ygc);
        acc2[dq] = __builtin_amdgcn_mfma_f32_16x16x32_f16(a0, bv, acc2[dq], 0, 0, 0);
      }
    }
  }

  // dump out-partial into OWN priv slice as f32 [i][d]
  {
    float* po = (float*)priv;
    #pragma unroll
    for (int dq = 0; dq < 4; ++dq)
      #pragma unroll
      for (int rr = 0; rr < 4; ++rr)
        po[(g*4 + rr)*64 + dq*16 + r16] = acc2[dq][rr];
  }

  __syncthreads();   // all priv partials + sAF complete

  // out: cross-head reduce, 512 threads x float2 -> full 64B lines
  {
    int e2 = t * 2;
    int i = e2 >> 6, d = e2 & 63;
    float sx = 0.f, sy = 0.f;
    #pragma unroll
    for (int h2 = 0; h2 < SH; ++h2) {
      const float* ph = (const float*)&sPriv[h2][0];
      sx += ph[i*64 + d];
      sy += ph[i*64 + d + 1];
    }
    *(float2*)(outp + ((size_t)b*SS + t0 + i)*64 + d) = make_float2(sx, sy);
  }

  // af: flat f16 -> f32 streaming copy (full lines)
  {
    float* afb = af + ((size_t)b*SS + t0) * (size_t)(SNO*SH);
    for (int idx = t; idx < TQ*SNO*SH/4; idx += 512) {
      const f16* s = &sAF[idx*4];
      float4 w = make_float4((float)s[0], (float)s[1], (float)s[2], (float)s[3]);
      *(float4*)(afb + idx*4) = w;
    }
  }
}

extern "C" void kernel_launch(void* const* d_in, const int* in_sizes, int n_in,
                              void* d_out, int out_size, void* d_ws, size_t ws_size,
                              hipStream_t stream) {
  const float* q    = (const float*)d_in[0];
  const float* k    = (const float*)d_in[1];
  const float* v    = (const float*)d_in[2];
  const float* Wq   = (const float*)d_in[3];
  const float* bq   = (const float*)d_in[4];
  const float* Wk   = (const float*)d_in[5];
  const float* bk   = (const float*)d_in[6];
  const float* ocpe = (const float*)d_in[7];

  // ws: Kf (8.39MB) + Vt (8.39MB) + Qf (8.39MB) = 25.2MB (fits proven 33.7MB)
  f16* Kf = (f16*)d_ws;
  f16* Vt = Kf + (size_t)SB*SH*SS*SD;
  f16* Qf = Vt + (size_t)SB*SH*SS*SD;

  float* af = (float*)d_out;
  float* op = af + (size_t)SB*SS*SNO*SH;

  prep_kernel<<<SB*SH*64, 256, 0, stream>>>(q, k, v, Wq, bq, Wk, bk, Qf, Kf, Vt);
  attn_fused<<<SB*NT16, 512, 0, stream>>>(Qf, Kf, Vt, ocpe, af, op);
}